// Round 9
// baseline (98.513 us; speedup 1.0000x reference)
//
#include <hip/hip_runtime.h>
#include <hip/hip_bf16.h>
#include <stdint.h>

typedef int i32x4 __attribute__((ext_vector_type(4)));

constexpr int IN_F = 1024;
constexpr int OUT_F = 1024;
constexpr int M_TOT = 8 * 4096;   // 32768 tokens
constexpr int K_TOT = IN_F;
constexpr int N_TOT = OUT_F;

// ---------------- kernel 1: per-token int8 fake-quant -> int8 q ----------------
__global__ __launch_bounds__(256) void quant_kernel(
    const float* __restrict__ x,
    const float* __restrict__ wscale,
    int8_t* __restrict__ q,            // [M_TOT][K_TOT] int8
    float* __restrict__ inv_row)       // [M_TOT]  (= a/127 * weight_scale)
{
    const int row = blockIdx.x;
    const int t = threadIdx.x;
    const float4 v = reinterpret_cast<const float4*>(x + (size_t)row * IN_F)[t];
    float m = fmaxf(fmaxf(fabsf(v.x), fabsf(v.y)), fmaxf(fabsf(v.z), fabsf(v.w)));
    #pragma unroll
    for (int off = 32; off > 0; off >>= 1)
        m = fmaxf(m, __shfl_xor(m, off));
    __shared__ float smax[4];
    if ((t & 63) == 0) smax[t >> 6] = m;
    __syncthreads();
    m = fmaxf(fmaxf(smax[0], smax[1]), fmaxf(smax[2], smax[3]));
    const float a = fmaxf(m, 1e-5f);
    const float as = 127.0f / a;

    char4 o;
    o.x = (char)(int)fminf(fmaxf(rintf(v.x * as), -128.0f), 127.0f);
    o.y = (char)(int)fminf(fmaxf(rintf(v.y * as), -128.0f), 127.0f);
    o.z = (char)(int)fminf(fmaxf(rintf(v.z * as), -128.0f), 127.0f);
    o.w = (char)(int)fminf(fmaxf(rintf(v.w * as), -128.0f), 127.0f);
    reinterpret_cast<char4*>(q + (size_t)row * IN_F)[t] = o;
    if (t == 0) inv_row[row] = (a / 127.0f) * wscale[0];
}

// ---------------- kernel 2: unpack ternary -> B in MFMA-fragment order ----------------
// wt2 layout: [kt(16)][col(1024)][kq(4)][kb(16)] so a wave's B-frag (col = base+(l&15),
// k = kt*64 + (l>>4)*16 ..+15) is one per-lane 16B contiguous load; the whole wave
// reads 1KB contiguous. value = ((packed[(o&255)*1024 + k] >> (2*(o>>8))) & 3) - 1.
__global__ __launch_bounds__(256) void unpack_kernel(
    const int* __restrict__ packed,
    int8_t* __restrict__ wt2)          // 1 MiB
{
    const int o = blockIdx.x;
    const int t = threadIdx.x;
    const int k0 = t * 4;
    const int sh = (o >> 8) * 2;
    const int pbase = ((o & 255) << 10) + k0;
    const int4 pw = *reinterpret_cast<const int4*>(packed + pbase);
    char4 r;
    r.x = (char)(((pw.x >> sh) & 3) - 1);
    r.y = (char)(((pw.y >> sh) & 3) - 1);
    r.z = (char)(((pw.z >> sh) & 3) - 1);
    r.w = (char)(((pw.w >> sh) & 3) - 1);
    // dest: kt = k0>>6, kq = (k0>>4)&3, kb = k0&15
    const int addr = (k0 >> 6) * 65536 + o * 64 + ((k0 >> 4) & 3) * 16 + (k0 & 15);
    *reinterpret_cast<char4*>(wt2 + addr) = r;
}

// ---------------- kernel 3: int8 MFMA GEMM, A-only LDS, B direct from L2 ----------------
// mfma_i32_16x16x64_i8. BM=256 x BN=128, BK=64. 8 waves (4M x 2N), 64x64/wave.
// LDS = A only, 3 slots x 16 KiB = 48 KiB -> 2 blocks/CU (VGPR<=128 via bounds(512,4)).
// B frags load straight to VGPR from fragment-ordered wt2 (L2-resident, coalesced 1KB
// per wave-request), double-buffered bX/bY, issued 2 K-tiles ahead AFTER last use.
// Per-CU per K-tile-step: MFMA 1306 cyc vs LDS ~835 cyc (96KB) -> MFMA-bound.
// vmcnt audit (stage=2 @s3, Bload=4 @s6 per iter): top-of-T outstanding =
// {A(T)2,B(T)4,A(T+1)2,B(T+1)4}=12, oldest2=A(T) -> vmcnt(10); T=NT-1 -> vmcnt(4).
// A swizzle: ch ^= (r>>1)&3 involution (2-way, free; r8-proven), linear LDS dest.
constexpr int BM = 256, BN = 128, BK = 64;
constexpr int NT = K_TOT / BK;   // 16

__global__ __launch_bounds__(512, 4) void gemm_kernel(
    const int8_t* __restrict__ qa,     // [M_TOT][K_TOT] int8
    const int8_t* __restrict__ wb2,    // fragment-ordered ternary weights (1 MiB)
    const float* __restrict__ inv_row,
    const float* __restrict__ bias,
    float* __restrict__ out)
{
    // XCD-aware swizzle: nwg = 1024, divisible by 8 -> bijective simple remap
    int bid = blockIdx.x;
    bid = (bid & 7) * ((int)gridDim.x >> 3) + (bid >> 3);
    const int tm = bid >> 3;            // 0..127
    const int tn = bid & 7;             // 0..7

    const int tid = threadIdx.x;
    const int lane = tid & 63;
    const int wid = tid >> 6;           // 0..7
    const int wr = wid >> 1;            // 0..3 (M quarter: rows wr*64..)
    const int wc = wid & 1;             // 0..1 (N half: cols wc*64..)

    __shared__ int8_t ldsA[3 * 256 * 64];   // 48 KiB

    const int rowA0 = tm * BM;
    const int rowB0 = tn * BN;
    const int frow = lane & 15;
    const int fq = lane >> 4;           // 0..3

    i32x4 acc[4][4] = {};

    // A staging: chunk c = j*512 + tid (16B); rl = c>>2, cc = c&3;
    // source chunk scc = cc ^ ((rl>>1)&3) -- j-invariant (j*128 even in bits 1..2).
    const int r0 = tid >> 2;
    const int scc0 = (tid & 3) ^ ((r0 >> 1) & 3);
    const int8_t* srcA0 = qa + (size_t)(rowA0 + r0) * K_TOT + scc0 * 16;
    const int dA0 = tid * 16, dA1 = (512 + tid) * 16;

    auto stageA = [&](int slot, int kt) {
        __builtin_amdgcn_global_load_lds(
            (const __attribute__((address_space(1))) void*)(srcA0 + kt * BK),
            (__attribute__((address_space(3))) void*)&ldsA[slot * 16384 + dA0], 16, 0, 0);
        __builtin_amdgcn_global_load_lds(
            (const __attribute__((address_space(1))) void*)(srcA0 + (size_t)128 * K_TOT + kt * BK),
            (__attribute__((address_space(3))) void*)&ldsA[slot * 16384 + dA1], 16, 0, 0);
    };

    auto ldA = [&](int slot, int mf) -> i32x4 {
        const int r = wr * 64 + mf * 16 + frow;
        const int ch = fq ^ ((r >> 1) & 3);
        return *reinterpret_cast<const i32x4*>(&ldsA[slot * 16384 + r * 64 + ch * 16]);
    };

    // B frag base: col = rowB0 + wc*64 + nf*16 + frow; addr = kt*65536 + col*64 + fq*16
    const int8_t* wbBase = wb2 + (size_t)(rowB0 + wc * 64 + frow) * 64 + fq * 16;
    auto loadB = [&](int kt, i32x4 (&b)[4]) {
        #pragma unroll
        for (int nf = 0; nf < 4; ++nf)
            b[nf] = *reinterpret_cast<const i32x4*>(wbBase + kt * 65536 + nf * 1024);
    };

    i32x4 bX[4], bY[4];

    // prologue: A(0), A(1) staged; B(0)->bX, B(1)->bY  (12 vmem ops outstanding)
    stageA(0, 0);
    stageA(1, 1);
    loadB(0, bX);
    loadB(1, bY);

    auto body = [&](int T, i32x4 (&bCur)[4]) {
        const int s = T % 3;
        if (T < NT - 1) asm volatile("s_waitcnt vmcnt(10)" ::: "memory");
        else            asm volatile("s_waitcnt vmcnt(4)" ::: "memory");
        __builtin_amdgcn_s_barrier();

        i32x4 aF[4];
        #pragma unroll
        for (int mf = 0; mf < 4; ++mf) aF[mf] = ldA(s, mf);

        if (T + 2 < NT) stageA((T + 2) % 3, T + 2);

        asm volatile("s_waitcnt lgkmcnt(0)" ::: "memory");
        __builtin_amdgcn_sched_barrier(0);
        __builtin_amdgcn_s_setprio(1);
        #pragma unroll
        for (int mf = 0; mf < 4; ++mf)
            #pragma unroll
            for (int nf = 0; nf < 4; ++nf)
                acc[mf][nf] = __builtin_amdgcn_mfma_i32_16x16x64_i8(
                    aF[mf], bCur[nf], acc[mf][nf], 0, 0, 0);
        __builtin_amdgcn_s_setprio(0);

        if (T + 2 < NT) loadB(T + 2, bCur);   // after last use of bCur
    };

    for (int t2 = 0; t2 < NT; t2 += 2) {
        body(t2, bX);
        body(t2 + 1, bY);
    }

    // epilogue: C/D 16x16 layout: col = lane&15, row = fq*4 + reg. acc exact in i32.
    #pragma unroll
    for (int mf = 0; mf < 4; ++mf) {
        #pragma unroll
        for (int j = 0; j < 4; ++j) {
            const int gm = rowA0 + wr * 64 + mf * 16 + fq * 4 + j;
            const float sc = inv_row[gm];
            #pragma unroll
            for (int nf = 0; nf < 4; ++nf) {
                const int gn = rowB0 + wc * 64 + nf * 16 + frow;
                out[(size_t)gm * N_TOT + gn] = (float)acc[mf][nf][j] * sc + bias[gn];
            }
        }
    }
}

extern "C" void kernel_launch(void* const* d_in, const int* in_sizes, int n_in,
                              void* d_out, int out_size, void* d_ws, size_t ws_size,
                              hipStream_t stream) {
    const float* x = (const float*)d_in[0];
    const int* packed = (const int*)d_in[1];
    const float* wscale = (const float*)d_in[2];
    const float* bias = (const float*)d_in[3];
    float* out = (float*)d_out;

    int8_t* q = (int8_t*)d_ws;                                          // 32 MiB
    int8_t* wt2 = (int8_t*)((char*)d_ws + (size_t)M_TOT * K_TOT);       // 1 MiB
    float* inv_row = (float*)((char*)d_ws + (size_t)M_TOT * K_TOT + (size_t)N_TOT * K_TOT);

    quant_kernel<<<M_TOT, 256, 0, stream>>>(x, wscale, q, inv_row);
    unpack_kernel<<<OUT_F, 256, 0, stream>>>(packed, wt2);
    gemm_kernel<<<(M_TOT / BM) * (N_TOT / BN), 512, 0, stream>>>(q, wt2, inv_row, bias, out);
}